// Round 16
// baseline (419.855 us; speedup 1.0000x reference)
//
#include <hip/hip_runtime.h>

// NNMF fused: B=8192, NIN=3072, NOUT=512, 5 iterations.
// R22: it0 produces X2 (bf16 x) as a staging side-product; it1-4 = R18 path.
//  R21 evidence: gap with no x-pass = 110 us (fixed overhead); x-norm pass
//  was only ~35 us; but fp32-x-every-iteration cost main +63 us (2x staging
//  bytes, x evicted from L3: FETCH +125 MB). R18's bf16-X2 it1-4 path is the
//  measured best. Fix: it0 stages fp32 x (exact, also accumulates rowsums
//  for the R21 rfac folding -- no normalize pass needed) and writes bf16 X2
//  from the registers already in hand (one 8B store per staged chunk).
//  it1-4 read X2 exactly like R18 (L3-resident). X2 write->read ordered by
//  one vmcnt(0) drain + re-prime at the it0 boundary (same-wave chunks).
//  Scales = R21 (verified): denom_acc = denom*2^21, DSCL2 = 2^-15 ->
//  r = x*2^-6/denom; rfac = 2^-6/rowsum at boundary. d0part contiguous [k][8].
//  prep = 192 W-blocks only (R20/R21 structure).

#define NIN 3072
#define NOUT 512

using f32x4 = __attribute__((ext_vector_type(4))) float;
using i32x8 = __attribute__((ext_vector_type(8))) int;

union frag32 { i32x8 v; uint4 q[2]; };

// A = fp8 e4m3, B = fp8 e4m3, scales = 2^0
#define MFMA128(A, B, C) \
    __builtin_amdgcn_mfma_scale_f32_16x16x128_f8f6f4( \
        (A), (B), (C), 0, 0, 0, (int)0x7f7f7f7f, 0, (int)0x7f7f7f7f)
// A = fp8 e4m3 (cbsz=0), B = fp6 e2m3 (blgp=2), scales = 2^0
#define MFMA128_F6(A, B, C) \
    __builtin_amdgcn_mfma_scale_f32_16x16x128_f8f6f4( \
        (A), (B), (C), 0, 2, 0, (int)0x7f7f7f7f, 0, (int)0x7f7f7f7f)

__device__ __forceinline__ unsigned short f2bf(float f) {
    unsigned int u = __builtin_bit_cast(unsigned int, f);
    return (unsigned short)((u + 0x7fffu + ((u >> 16) & 1u)) >> 16);  // RNE
}
__device__ __forceinline__ float bf2f(unsigned short s) {
    unsigned int u = ((unsigned int)s) << 16;
    return __builtin_bit_cast(float, u);
}
__device__ __forceinline__ ushort4 f2bf4(uint4 u) {
    float4 f = __builtin_bit_cast(float4, u);
    ushort4 o;
    o.x = f2bf(f.x); o.y = f2bf(f.y); o.z = f2bf(f.z); o.w = f2bf(f.w);
    return o;
}

// e2m3 encode of nonnegative p (caller guarantees p <= 7.75)
__device__ __forceinline__ unsigned enc_fp6(float p) {
    if (p < 1.9375f) {                 // denormal + e=1: step 0.125, codes 0..15
        int q = (int)rintf(p * 8.0f);
        return (unsigned)q;
    }
    if (p < 3.875f) {                  // e=2: step 0.25, codes 16..23
        int m = (int)rintf((p - 2.0f) * 4.0f);
        return (m > 7) ? 24u : (16u + (unsigned)m);
    }
    int m = (int)rintf((p - 4.0f) * 2.0f);  // e=3: step 0.5, codes 24..31
    if (m > 7) m = 7;
    return 24u + (unsigned)m;
}

// load a 24-byte fp6 fragment (8B-aligned) into the low 6 dwords
__device__ __forceinline__ void load6(frag32& f, const unsigned char* p) {
    const uint2* q = reinterpret_cast<const uint2*>(p);
    uint2 a = q[0], b = q[1], c = q[2];
    f.v = (i32x8){(int)a.x, (int)a.y, (int)b.x, (int)b.y, (int)c.x, (int)c.y, 0, 0};
}

// LDS-only barrier: cross-wave deps in the slot loop are LDS-only; global
// prefetches stay in flight (consumed by issuing wave, compiler inserts vmcnt).
#define LDS_BARRIER() do {                                   \
    asm volatile("s_waitcnt lgkmcnt(0)" ::: "memory");       \
    __builtin_amdgcn_s_barrier();                            \
    asm volatile("" ::: "memory");                           \
} while (0)

// ---------------------------------------------------------------------------
// prep_w: 192 blocks x 256 threads, one block per (s-slice, 64-row n-chunk):
//   coalesced float4 read of W[nc*64..+64][s*128..+128] into LDS, then emit
//   W2 fp8 frags, W1 fp6 frags, and d0part[k][nc] partials.
// Frag layouts (R18; lane l holds 32 contiguous contraction elements,
// k = (l>>4)*32 + j):
//   W2 (fp8 32B): byte = ((s*32 + ntile)*64 + l)*32 + j
//     element: n = ntile*16 + (l&15), k = s*128 + (l>>4)*32 + j
//   W1 (fp6 24B): frag = ((s*8 + w8)*4 + c)*64 + l, byte = frag*24,
//     element j at bits [6j+5:6j]: kout = s*128 + w8*16 + (l&15),
//     n = c*128 + (l>>4)*32 + j
//   d0part[k*8 + nch] = sum_{n in chunk nch} h0[n]*W[n][k]  (fp32, contiguous)
// ---------------------------------------------------------------------------
__global__ void prep_w(const float* __restrict__ W,
                       const float* __restrict__ h_init,
                       unsigned char* __restrict__ W1,
                       unsigned char* __restrict__ W2,
                       float* __restrict__ d0part) {
    __shared__ float tile[64][132];   // 33.8 KB W staging
    const int bb = blockIdx.x;
    const int t  = threadIdx.x;
    const int s  = bb >> 3, nc = bb & 7;
    const int n0 = nc * 64, k0 = s * 128;

    // ---- coalesced load: 8 passes x (8 rows x 32 float4)
    {
        int r8 = t >> 5, c4 = (t & 31) << 2;
        #pragma unroll
        for (int pass = 0; pass < 8; ++pass) {
            int r = pass * 8 + r8;
            float4 v = *reinterpret_cast<const float4*>(
                &W[(size_t)(n0 + r) * NIN + k0 + c4]);
            tile[r][c4] = v.x; tile[r][c4 + 1] = v.y;
            tile[r][c4 + 2] = v.z; tile[r][c4 + 3] = v.w;
        }
    }
    __syncthreads();

    // ---- W2 fp8 frags: thread = (ntl = t>>6, l = t&63)
    {
        int ntl = t >> 6, l = t & 63, lo = l & 15, hi = l >> 4;
        int n_loc = ntl * 16 + lo;
        int kk = hi * 32;
        unsigned int words[8];
        #pragma unroll
        for (int q = 0; q < 8; ++q) {
            float v0 = tile[n_loc][kk + q * 4 + 0] * 4096.0f;
            float v1 = tile[n_loc][kk + q * 4 + 1] * 4096.0f;
            float v2 = tile[n_loc][kk + q * 4 + 2] * 4096.0f;
            float v3 = tile[n_loc][kk + q * 4 + 3] * 4096.0f;
            int pk = __builtin_amdgcn_cvt_pk_fp8_f32(v0, v1, 0, false);
            pk     = __builtin_amdgcn_cvt_pk_fp8_f32(v2, v3, pk, true);
            words[q] = (unsigned int)pk;
        }
        uint4* dst = reinterpret_cast<uint4*>(
            W2 + ((size_t)((s * 32 + nc * 4 + ntl) * 64 + l)) * 32);
        dst[0] = *reinterpret_cast<uint4*>(&words[0]);
        dst[1] = *reinterpret_cast<uint4*>(&words[4]);
    }

    // ---- W1 fp6 frags: thread = (w8 = t>>5, l15 = t&15, hs = (t>>4)&1)
    {
        int w8 = t >> 5, r5 = t & 31, l15 = r5 & 15, hs = r5 >> 4;
        int hi = ((nc & 1) << 1) + hs;     // lane hi for this block's n-range
        int l  = hi * 16 + l15;
        int c  = nc >> 1;
        int kout_loc = w8 * 16 + l15;
        unsigned int dw[6] = {0, 0, 0, 0, 0, 0};
        #pragma unroll
        for (int j = 0; j < 32; ++j) {
            float p = tile[hs * 32 + j][kout_loc] * 8192.0f;
            unsigned c6 = enc_fp6(p);
            int bit = 6 * j, di = bit >> 5, off = bit & 31;
            dw[di] |= c6 << off;
            if (off > 26) dw[di + 1] |= c6 >> (32 - off);
        }
        uint2* d2 = reinterpret_cast<uint2*>(
            W1 + ((size_t)(((s * 8 + w8) * 4 + c) * 64 + l)) * 24);
        d2[0] = make_uint2(dw[0], dw[1]);
        d2[1] = make_uint2(dw[2], dw[3]);
        d2[2] = make_uint2(dw[4], dw[5]);
    }

    // ---- d0part: 128 threads, k-column sums over the 64 staged rows
    if (t < 128) {
        float ssum = 0.f;
        #pragma unroll 8
        for (int r = 0; r < 64; ++r)
            ssum += h_init[n0 + r] * tile[r][t];
        d0part[(size_t)(k0 + t) * 8 + nc] = ssum;
    }
}

// ---------------------------------------------------------------------------
// Main kernel. 256 blocks x 512 threads (8 waves), 32 rows/block, 1 block/CU.
// Two-barrier slots. it0: fp32 x staged + bf16 X2 emitted + rowsums.
// it1-4: R18 bf16 staging from X2. Phase A fp8xfp6, Phase B fp8.
// ---------------------------------------------------------------------------
__global__ __launch_bounds__(512, 1) void nnmf_main(
    const float* __restrict__ x,
    unsigned short* __restrict__ X2,
    const unsigned char* __restrict__ W1,
    const unsigned char* __restrict__ W2,
    const float* __restrict__ d0part,
    const float* __restrict__ h_init,
    float* __restrict__ out)
{
    __shared__ unsigned char  h8_lds[32 * 528];   // 16.9 KB (fp8 h, x256)
    __shared__ float          h32_lds[32 * 516];  // 66.0 KB (fp32 h master)
    __shared__ __align__(16) unsigned char xbuf[32 * 132 * 4];  // 16.9 KB
    // xbuf views: it0 = fp32 [32][132]; it1-4 = bf16 [32][136]
    __shared__ unsigned char  r8_lds[32 * 144];   //  4.6 KB (fp8 r, stride 144B)
    __shared__ float red[8][32];
    __shared__ float rfac_lds[32];                // 2^-6 / rowsum
    // total ~105.7 KB

    float* x32 = reinterpret_cast<float*>(xbuf);
    unsigned short* x16 = reinterpret_cast<unsigned short*>(xbuf);

    const int tid = threadIdx.x;
    const int w  = tid >> 6;        // wave 0..7
    const int l  = tid & 63;
    const int lo = l & 15;
    const int hi = l >> 4;          // 0..3
    const int b0 = blockIdx.x * 32;

    // fp32 h master init (LDS; each (row,col) owned by one thread at boundary)
    for (int idx = tid; idx < 32 * 512; idx += 512) {
        int r = idx >> 9, c = idx & 511;
        h32_lds[r * 516 + c] = h_init[c];
    }

    // x staging: thread -> (row = tid>>4, chunk xcc = tid&15)
    const int xrow = tid >> 4, xcc = tid & 15;
    const uint4* xg32 = reinterpret_cast<const uint4*>(x + (size_t)(b0 + xrow) * NIN);
    const uint4* xg16 = reinterpret_cast<const uint4*>(X2 + (size_t)(b0 + xrow) * NIN + xcc * 8);
    unsigned short* x2w = X2 + (size_t)(b0 + xrow) * NIN;
    float* x32dstA = &x32[xrow * 132 + xcc * 4];
    float* x32dstB = &x32[xrow * 132 + 64 + xcc * 4];
    unsigned short* x16dst = &x16[xrow * 136 + xcc * 8];

    // W pointers
    const unsigned char* w1base = W1 + ((size_t)(w * 4) * 64 + l) * 24;  // +s*49152 +c*1536 (fp6)
    const unsigned char* w2base = W2 + (size_t)w * 8192 + (size_t)l * 32; // +s*65536 +nt*2048 (fp8)

    // prologue (it0): stage fp32 slot0 -> LDS, emit X2 slot0, prefetch slot1
    {
        uint4 a0 = xg32[xcc], a1 = xg32[16 + xcc];
        *reinterpret_cast<uint4*>(x32dstA) = a0;
        *reinterpret_cast<uint4*>(x32dstB) = a1;
        *reinterpret_cast<ushort4*>(x2w + xcc * 4) = f2bf4(a0);
        *reinterpret_cast<ushort4*>(x2w + 64 + xcc * 4) = f2bf4(a1);
    }
    uint4 xnA = xg32[32 + xcc], xnB = xg32[48 + xcc];
    uint4 xn16;                     // bf16 prefetch (primed at it0 boundary)
    frag32 w1buf[4];                // Phase A B-frags fp6 (valid from it0 s==23 on)
    __syncthreads();

    const float DSCL2 = 3.0517578125e-05f;  // 2^-15: (h 2^8 * W1 2^13) -> denom*2^6
    f32x4 tacc[2][4];
    float xs0[4], xs1[4];           // it0 rowsum partials
    #pragma unroll
    for (int i = 0; i < 4; ++i) { xs0[i] = 0.f; xs1[i] = 0.f; }

    for (int it = 0; it < 5; ++it) {
        #pragma unroll
        for (int m = 0; m < 2; ++m)
            #pragma unroll
            for (int nt = 0; nt < 4; ++nt)
                tacc[m][nt] = (f32x4){0.f, 0.f, 0.f, 0.f};

        for (int s = 0; s < 24; ++s) {
            const int sn  = (s + 1 == 24) ? 0 : s + 1;
            const int sn2 = (s + 2 >= 24) ? (s + 2 - 24) : s + 2;

            // ---- issue W2[s] loads (4 x 32B fp8 frags; consumed after barrier A)
            frag32 w2v[4];
            {
                const unsigned char* w2p = w2base + (size_t)s * 65536;
                #pragma unroll
                for (int nt = 0; nt < 4; ++nt) {
                    const uint4* p = reinterpret_cast<const uint4*>(w2p + nt * 2048);
                    w2v[nt].q[0] = p[0];
                    w2v[nt].q[1] = p[1];
                }
            }

            f32x4 d0 = {0,0,0,0}, d1 = {0,0,0,0};
            float dv = 0.f;
            if (it == 0) {
                // exact it0 denom: 8 contiguous partials + precise div; dv incl 2^-6
                const float4* dp4 = reinterpret_cast<const float4*>(
                    d0part + (size_t)(s * 128 + w * 16 + lo) * 8);
                float4 a = dp4[0], b = dp4[1];
                float sm = 1e-20f + a.x + a.y + a.z + a.w + b.x + b.y + b.z + b.w;
                dv = 0.015625f / sm;
            } else {
                // ---- Phase A: h fp8 (A) x W1 fp6 (B), minimal transients
                #pragma unroll
                for (int c = 0; c < 4; ++c) {
                    frag32 ha0, ha1;
                    const uint4* p0 = reinterpret_cast<const uint4*>(
                        &h8_lds[lo * 528 + c * 128 + hi * 32]);
                    const uint4* p1 = reinterpret_cast<const uint4*>(
                        &h8_lds[(16 + lo) * 528 + c * 128 + hi * 32]);
                    ha0.q[0] = p0[0]; ha0.q[1] = p0[1];
                    ha1.q[0] = p1[0]; ha1.q[1] = p1[1];
                    d0 = MFMA128_F6(ha0.v, w1buf[c].v, d0);
                    d1 = MFMA128_F6(ha1.v, w1buf[c].v, d1);
                }
            }

            // ---- r -> fp8 in r8_lds (r = x*2^-6/denom; 2^-6 in DSCL2/dv)
            if (it == 0) {
                #pragma unroll
                for (int i = 0; i < 4; ++i) {
                    int row0 = hi * 4 + i;
                    float x0 = x32[row0 * 132 + w * 16 + lo];
                    float x1 = x32[(16 + row0) * 132 + w * 16 + lo];
                    xs0[i] += x0; xs1[i] += x1;   // rowsum accumulation
                    float r0 = x0 * dv, r1 = x1 * dv;
                    int c0 = __builtin_amdgcn_cvt_pk_fp8_f32(r0, r0, 0, false);
                    int c1 = __builtin_amdgcn_cvt_pk_fp8_f32(r1, r1, 0, false);
                    r8_lds[row0 * 144 + w * 16 + lo] = (unsigned char)(c0 & 0xff);
                    r8_lds[(16 + row0) * 144 + w * 16 + lo] = (unsigned char)(c1 & 0xff);
                }
            } else {
                #pragma unroll
                for (int i = 0; i < 4; ++i) {
                    int row0 = hi * 4 + i;
                    float x0 = bf2f(x16[row0 * 136 + w * 16 + lo]);
                    float x1 = bf2f(x16[(16 + row0) * 136 + w * 16 + lo]);
                    float r0 = x0 * __builtin_amdgcn_rcpf(fmaf(d0[i], DSCL2, 1e-20f));
                    float r1 = x1 * __builtin_amdgcn_rcpf(fmaf(d1[i], DSCL2, 1e-20f));
                    int c0 = __builtin_amdgcn_cvt_pk_fp8_f32(r0, r0, 0, false);
                    int c1 = __builtin_amdgcn_cvt_pk_fp8_f32(r1, r1, 0, false);
                    r8_lds[row0 * 144 + w * 16 + lo] = (unsigned char)(c0 & 0xff);
                    r8_lds[(16 + row0) * 144 + w * 16 + lo] = (unsigned char)(c1 & 0xff);
                }
            }
            LDS_BARRIER();   // barrier A (LDS-only: global prefetches stay in flight)

            // ---- Phase B: r8 frags (fp8) x w2v (fp8)
            frag32 ra0, ra1;
            {
                const uint4* p0 = reinterpret_cast<const uint4*>(&r8_lds[lo * 144 + hi * 32]);
                const uint4* p1 = reinterpret_cast<const uint4*>(&r8_lds[(16 + lo) * 144 + hi * 32]);
                ra0.q[0] = p0[0]; ra0.q[1] = p0[1];
                ra1.q[0] = p1[0]; ra1.q[1] = p1[1];
            }
            #pragma unroll
            for (int nt = 0; nt < 2; ++nt) {
                tacc[0][nt] = MFMA128(ra0.v, w2v[nt].v, tacc[0][nt]);
                tacc[1][nt] = MFMA128(ra1.v, w2v[nt].v, tacc[1][nt]);
            }

            // ---- reload w1buf = W1[sn] fp6 (skip during it0 except last slot)
            if (it > 0 || s == 23) {
                const unsigned char* w1p = w1base + (size_t)sn * 49152;
                #pragma unroll
                for (int c = 0; c < 4; ++c)
                    load6(w1buf[c], w1p + c * 1536);
            }

            #pragma unroll
            for (int nt = 2; nt < 4; ++nt) {
                tacc[0][nt] = MFMA128(ra0.v, w2v[nt].v, tacc[0][nt]);
                tacc[1][nt] = MFMA128(ra1.v, w2v[nt].v, tacc[1][nt]);
            }

            // ---- staging
            if (it == 0) {
                if (s < 23) {
                    // stage fp32 slot s+1; emit X2 slot s+1 from the same regs
                    *reinterpret_cast<uint4*>(x32dstA) = xnA;
                    *reinterpret_cast<uint4*>(x32dstB) = xnB;
                    *reinterpret_cast<ushort4*>(x2w + (s + 1) * 128 + xcc * 4) = f2bf4(xnA);
                    *reinterpret_cast<ushort4*>(x2w + (s + 1) * 128 + 64 + xcc * 4) = f2bf4(xnB);
                    if (s < 22) {
                        xnA = xg32[(s + 2) * 32 + xcc];
                        xnB = xg32[(s + 2) * 32 + 16 + xcc];
                    }
                }
            } else {
                *reinterpret_cast<uint4*>(x16dst) = xn16;
                xn16 = xg16[(size_t)sn2 * 16];
            }
            LDS_BARRIER();   // barrier B
        }

        // ---- it0 epilogue: rowsums -> rfac; drain X2 writes; re-prime bf16
        if (it == 0) {
            #pragma unroll
            for (int mask = 1; mask < 16; mask <<= 1)
                #pragma unroll
                for (int i = 0; i < 4; ++i) {
                    xs0[i] += __shfl_xor(xs0[i], mask, 64);
                    xs1[i] += __shfl_xor(xs1[i], mask, 64);
                }
            if (lo == 0) {
                #pragma unroll
                for (int i = 0; i < 4; ++i) {
                    red[w][hi * 4 + i]      = xs0[i];
                    red[w][16 + hi * 4 + i] = xs1[i];
                }
            }
            __syncthreads();
            if (tid < 32) {
                float sme = 1e-20f;
                #pragma unroll
                for (int ww = 0; ww < 8; ++ww) sme += red[ww][tid];
                rfac_lds[tid] = 0.015625f / sme;
            }
            __syncthreads();
            // drain this wave's X2 stores, then re-prime bf16 staging:
            // x16 slot0 -> LDS, slot1 -> register (same-wave chunks).
            asm volatile("s_waitcnt vmcnt(0)" ::: "memory");
            uint4 v0 = xg16[0];
            *reinterpret_cast<uint4*>(x16dst) = v0;
            xn16 = xg16[16];
        }

        // ---- boundary: h_new = normalize(h * (1 + tacc*rfac)), fp32 master in LDS
        float hv_[2][4][4];
        float p[2][4];
        float rf[2][4];
        #pragma unroll
        for (int m = 0; m < 2; ++m)
            #pragma unroll
            for (int i = 0; i < 4; ++i) {
                p[m][i] = 0.f;
                rf[m][i] = rfac_lds[m * 16 + hi * 4 + i];
            }

        #pragma unroll
        for (int m = 0; m < 2; ++m)
            #pragma unroll
            for (int nt = 0; nt < 4; ++nt)
                #pragma unroll
                for (int i = 0; i < 4; ++i) {
                    int row = m * 16 + hi * 4 + i;
                    int col = w * 64 + nt * 16 + lo;
                    float hv = h32_lds[row * 516 + col];
                    float v = hv * fmaf(tacc[m][nt][i], rf[m][i], 1.0f);  // EPSILON_0 = 1
                    hv_[m][nt][i] = v;
                    p[m][i] += v;
                }
        #pragma unroll
        for (int mask = 1; mask < 16; mask <<= 1)
            #pragma unroll
            for (int m = 0; m < 2; ++m)
                #pragma unroll
                for (int i = 0; i < 4; ++i)
                    p[m][i] += __shfl_xor(p[m][i], mask, 64);
        if (lo == 0) {
            #pragma unroll
            for (int m = 0; m < 2; ++m)
                #pragma unroll
                for (int i = 0; i < 4; ++i)
                    red[w][m * 16 + hi * 4 + i] = p[m][i];
        }
        __syncthreads();
        float inv[2][4];
        #pragma unroll
        for (int m = 0; m < 2; ++m)
            #pragma unroll
            for (int i = 0; i < 4; ++i) {
                int row = m * 16 + hi * 4 + i;
                float S = 0.f;
                #pragma unroll
                for (int ww = 0; ww < 8; ++ww) S += red[ww][row];
                inv[m][i] = 1.f / (S + 1e-20f);
            }

        if (it < 4) {
            #pragma unroll
            for (int m = 0; m < 2; ++m)
                #pragma unroll
                for (int nt = 0; nt < 4; ++nt)
                    #pragma unroll
                    for (int i = 0; i < 4; ++i) {
                        int row = m * 16 + hi * 4 + i;
                        int col = w * 64 + nt * 16 + lo;
                        float hv = hv_[m][nt][i] * inv[m][i];
                        h32_lds[row * 516 + col] = hv;
                        int c = __builtin_amdgcn_cvt_pk_fp8_f32(hv * 256.0f, hv * 256.0f, 0, false);
                        h8_lds[row * 528 + col] = (unsigned char)(c & 0xff);
                    }
            __syncthreads();
        } else {
            #pragma unroll
            for (int m = 0; m < 2; ++m)
                #pragma unroll
                for (int nt = 0; nt < 4; ++nt)
                    #pragma unroll
                    for (int i = 0; i < 4; ++i) {
                        int row = m * 16 + hi * 4 + i;
                        int col = w * 64 + nt * 16 + lo;
                        out[(size_t)(b0 + row) * 512 + col] = hv_[m][nt][i] * inv[m][i];
                    }
        }
    }
}

extern "C" void kernel_launch(void* const* d_in, const int* in_sizes, int n_in,
                              void* d_out, int out_size, void* d_ws, size_t ws_size,
                              hipStream_t stream) {
    const float* x   = (const float*)d_in[0];   // [8192][3072]
    const float* wgt = (const float*)d_in[1];   // [512][3072]
    const float* h0  = (const float*)d_in[2];   // [512]
    float* out = (float*)d_out;

    // ws: X2 bf16 50,331,648 | W1 fp6 1,179,648 | W2 fp8 1,572,864 | d0part 98,304
    unsigned short* X2 = (unsigned short*)d_ws;
    unsigned char*  W1 = (unsigned char*)((char*)d_ws + 50331648);
    unsigned char*  W2 = (unsigned char*)((char*)d_ws + 51511296);
    float* d0part      = (float*)((char*)d_ws + 53084160);

    prep_w<<<192, 256, 0, stream>>>(wgt, h0, W1, W2, d0part);
    nnmf_main<<<256, 512, 0, stream>>>(x, X2, W1, W2, d0part, h0, out);
}

// Round 17
// 381.585 us; speedup vs baseline: 1.1003x; 1.1003x over previous
//
#include <hip/hip_runtime.h>

// NNMF fused: B=8192, NIN=3072, NOUT=512, 5 iterations.
// R23 = R18 verbatim (measured session best: main 234.2 us, total 381.3 us).
//  Session map (16 measured variants):
//   - scheduling tricks (R8/R12/R13/R15/R16): all regressed -> two-barrier
//     slot rhythm with loads at region tops is the local optimum.
//   - pipe shrinking: MX K=128 (R11, +73us) and fp6 W1 (R18, +6us) won;
//     fp6 W2 fails numerics (R17: quant error enters t as sqrt(3072)-term
//     sum). W-pipe now at 24 B/cy << 56 B/cy L2 share -- exhausted.
//   - occupancy (R9/R10/R19): compiler pins VGPR=128 (remat) or spills at
//     1024 thr (64-reg target, 287MB scratch) -- not actionable at source.
//   - prep/x-pass restructuring (R20/R21/R22): gap floor = ~110us fixed
//     overhead + ~35us x-pass; every x-pass deletion cost main more than
//     it saved (L3 eviction / dual-path codegen).
//  Structure: 256 blocks x 512 thr, 32 rows/block; two-barrier slots;
//  h fp32 master in LDS (boundary-only); Phase A = h fp8 x W1 fp6 e2m3
//  (x2^13, blgp=2); Phase B = r fp8 x W2 fp8 e4m3 (x2^12); exact-it0 d0inv;
//  x pre-scaled x16 bf16.

#define NIN 3072
#define NOUT 512

using f32x4 = __attribute__((ext_vector_type(4))) float;
using i32x8 = __attribute__((ext_vector_type(8))) int;

union frag32 { i32x8 v; uint4 q[2]; };

// A = fp8 e4m3, B = fp8 e4m3, scales = 2^0
#define MFMA128(A, B, C) \
    __builtin_amdgcn_mfma_scale_f32_16x16x128_f8f6f4( \
        (A), (B), (C), 0, 0, 0, (int)0x7f7f7f7f, 0, (int)0x7f7f7f7f)
// A = fp8 e4m3 (cbsz=0), B = fp6 e2m3 (blgp=2), scales = 2^0
#define MFMA128_F6(A, B, C) \
    __builtin_amdgcn_mfma_scale_f32_16x16x128_f8f6f4( \
        (A), (B), (C), 0, 2, 0, (int)0x7f7f7f7f, 0, (int)0x7f7f7f7f)

__device__ __forceinline__ unsigned short f2bf(float f) {
    unsigned int u = __builtin_bit_cast(unsigned int, f);
    return (unsigned short)((u + 0x7fffu + ((u >> 16) & 1u)) >> 16);  // RNE
}
__device__ __forceinline__ float bf2f(unsigned short s) {
    unsigned int u = ((unsigned int)s) << 16;
    return __builtin_bit_cast(float, u);
}

// e2m3 encode of nonnegative p (caller guarantees p <= 7.75)
__device__ __forceinline__ unsigned enc_fp6(float p) {
    if (p < 1.9375f) {                 // denormal + e=1: step 0.125, codes 0..15
        int q = (int)rintf(p * 8.0f);
        return (unsigned)q;
    }
    if (p < 3.875f) {                  // e=2: step 0.25, codes 16..23
        int m = (int)rintf((p - 2.0f) * 4.0f);
        return (m > 7) ? 24u : (16u + (unsigned)m);
    }
    int m = (int)rintf((p - 4.0f) * 2.0f);  // e=3: step 0.5, codes 24..31
    if (m > 7) m = 7;
    return 24u + (unsigned)m;
}

// load a 24-byte fp6 fragment (8B-aligned) into the low 6 dwords
__device__ __forceinline__ void load6(frag32& f, const unsigned char* p) {
    const uint2* q = reinterpret_cast<const uint2*>(p);
    uint2 a = q[0], b = q[1], c = q[2];
    f.v = (i32x8){(int)a.x, (int)a.y, (int)b.x, (int)b.y, (int)c.x, (int)c.y, 0, 0};
}

// LDS-only barrier: cross-wave deps in the slot loop are LDS-only; global
// prefetches stay in flight (consumed by issuing wave, compiler inserts vmcnt).
#define LDS_BARRIER() do {                                   \
    asm volatile("s_waitcnt lgkmcnt(0)" ::: "memory");       \
    __builtin_amdgcn_s_barrier();                            \
    asm volatile("" ::: "memory");                           \
} while (0)

// ---------------------------------------------------------------------------
// prep_all: one launch, 8672 blocks x 256 threads.
//   blocks [0,8192)     : per-row x normalize (x16 pre-scale) -> bf16 X2
//   blocks [8192,8576)  : W -> W2 (fp8 x4096) / W1 (fp6 e2m3 x8192)
//   blocks [8576,8672)  : d0inv[k] = 1/(sum_n h0[n]*W[n][k] + 1e-20)  (exact fp32)
// K=128 fragment layouts (lane l holds 32 contiguous contraction elements,
// k = (l>>4)*32 + j):
//   W2 (Phase B B-op, fp8 32B): byte = ((s*32 + w*4 + nt)*64 + l)*32 + j
//     element: n = w*64 + nt*16 + (l&15), k = s*128 + (l>>4)*32 + j
//   W1 (Phase A B-op, fp6 24B): frag = ((s*8 + w)*4 + c)*64 + l, byte = frag*24,
//     element j at bits [6j+5:6j]: kout = s*128 + w*16 + (l&15), n = c*128 + (l>>4)*32 + j
// ---------------------------------------------------------------------------
__global__ void prep_all(const float* __restrict__ x,
                         const float* __restrict__ W,
                         const float* __restrict__ h_init,
                         unsigned short* __restrict__ X2,
                         unsigned char* __restrict__ W1,
                         unsigned char* __restrict__ W2,
                         float* __restrict__ d0inv) {
    __shared__ float wsum[4];
    __shared__ float dred[8][32];
    const int bb = blockIdx.x;
    const int t  = threadIdx.x;

    if (bb < 8192) {
        // ---- x row normalize -> bf16, pre-scaled x16 (exact: power of 2)
        const int b = bb;
        const float4* r4 = reinterpret_cast<const float4*>(x + (size_t)b * NIN);
        float s = 0.f;
        float4 v0 = r4[t], v1 = r4[t + 256], v2 = r4[t + 512];
        s = v0.x + v0.y + v0.z + v0.w + v1.x + v1.y + v1.z + v1.w + v2.x + v2.y + v2.z + v2.w;
        #pragma unroll
        for (int off = 32; off > 0; off >>= 1) s += __shfl_down(s, off, 64);
        int w = t >> 6, l = t & 63;
        if (l == 0) wsum[w] = s;
        __syncthreads();
        float inv = 16.0f / (wsum[0] + wsum[1] + wsum[2] + wsum[3] + 1e-20f);
        unsigned short* orow = X2 + (size_t)b * NIN;
        #pragma unroll
        for (int c = 0; c < 3; ++c) {
            float4 v = (c == 0) ? v0 : (c == 1) ? v1 : v2;
            ushort4 o;
            o.x = f2bf(v.x * inv); o.y = f2bf(v.y * inv);
            o.z = f2bf(v.z * inv); o.w = f2bf(v.w * inv);
            *reinterpret_cast<ushort4*>(orow + (t + c * 256) * 4) = o;
        }
    } else if (bb < 8192 + 384) {
        int tt = (bb - 8192) * 256 + t;       // 0 .. 98303
        if (tt < 49152) {
            // ---- W2 fp8 x4096
            int l = tt & 63, g = tt >> 6;
            int s = g >> 5, rem = g & 31, w = rem >> 2, nt = rem & 3;
            int n = w * 64 + nt * 16 + (l & 15);
            int kbase = s * 128 + ((l >> 4) << 5);
            const float* src = W + (size_t)n * NIN + kbase;
            unsigned int words[8];
            #pragma unroll
            for (int q = 0; q < 8; ++q) {
                float v0 = src[q * 4 + 0] * 4096.0f, v1 = src[q * 4 + 1] * 4096.0f;
                float v2 = src[q * 4 + 2] * 4096.0f, v3 = src[q * 4 + 3] * 4096.0f;
                int pk = __builtin_amdgcn_cvt_pk_fp8_f32(v0, v1, 0, false);
                pk     = __builtin_amdgcn_cvt_pk_fp8_f32(v2, v3, pk, true);
                words[q] = (unsigned int)pk;
            }
            uint4* dst = reinterpret_cast<uint4*>(W2 + (size_t)tt * 32);
            dst[0] = *reinterpret_cast<uint4*>(&words[0]);
            dst[1] = *reinterpret_cast<uint4*>(&words[4]);
        } else {
            // ---- W1 fp6 e2m3 x8192 (24 B per fragment)
            int u = tt - 49152;
            int l = u & 63, g = u >> 6;
            int c = g & 3, sw = g >> 2;
            int w = sw & 7, s = sw >> 3;
            int kout = s * 128 + w * 16 + (l & 15);
            int nbase = c * 128 + ((l >> 4) << 5);
            float v[32];
            #pragma unroll
            for (int j = 0; j < 32; ++j)
                v[j] = W[(size_t)(nbase + j) * NIN + kout] * 8192.0f;
            unsigned int dw[6] = {0, 0, 0, 0, 0, 0};
            #pragma unroll
            for (int j = 0; j < 32; ++j) {
                unsigned c6 = enc_fp6(v[j]);
                int bit = 6 * j, di = bit >> 5, off = bit & 31;
                dw[di] |= c6 << off;
                if (off > 26) dw[di + 1] |= c6 >> (32 - off);
            }
            uint2* d2 = reinterpret_cast<uint2*>(W1 + (size_t)u * 24);
            d2[0] = make_uint2(dw[0], dw[1]);
            d2[1] = make_uint2(dw[2], dw[3]);
            d2[2] = make_uint2(dw[4], dw[5]);
        }
    } else {
        // ---- d0inv: block owns 32 k-cols; thread (kid = t&31, nsub = t>>5)
        int kb = bb - 8576;                   // 0..95
        int kid = t & 31, nsub = t >> 5;      // 8 n-chunks of 64
        int k = kb * 32 + kid;
        int n0 = nsub * 64;
        float s = 0.f;
        const float* p = W + (size_t)n0 * NIN + k;
        #pragma unroll 8
        for (int n = 0; n < 64; ++n) s += h_init[n0 + n] * p[(size_t)n * NIN];
        dred[nsub][kid] = s;
        __syncthreads();
        if (t < 32) {
            float sm = 1e-20f;
            #pragma unroll
            for (int j = 0; j < 8; ++j) sm += dred[j][t];
            d0inv[kb * 32 + t] = 1.0f / sm;
        }
    }
}

// ---------------------------------------------------------------------------
// Main kernel. 256 blocks x 512 threads (8 waves), 32 rows/block, 1 block/CU.
// R14 two-barrier slot structure; h master in LDS; Phase A fp8xfp6, Phase B fp8.
// ---------------------------------------------------------------------------
__global__ __launch_bounds__(512, 1) void nnmf_main(
    const unsigned short* __restrict__ X2,
    const unsigned char* __restrict__ W1,
    const unsigned char* __restrict__ W2,
    const float* __restrict__ d0inv,
    const float* __restrict__ h_init,
    float* __restrict__ out)
{
    __shared__ unsigned char  h8_lds[32 * 528];   // 16.9 KB (fp8 h, x256)
    __shared__ float          h32_lds[32 * 516];  // 66.0 KB (fp32 h master)
    __shared__ unsigned short x_lds[32 * 136];    //  8.7 KB
    __shared__ unsigned char  r8_lds[32 * 144];   //  4.6 KB (fp8 r, stride 144B)
    __shared__ float red[8][32];
    // total ~97.3 KB

    const int tid = threadIdx.x;
    const int w  = tid >> 6;        // wave 0..7
    const int l  = tid & 63;
    const int lo = l & 15;
    const int hi = l >> 4;          // 0..3
    const int b0 = blockIdx.x * 32;

    // fp32 h master init (LDS; each (row,col) owned by one thread at boundary)
    for (int idx = tid; idx < 32 * 512; idx += 512) {
        int r = idx >> 9, c = idx & 511;
        h32_lds[r * 516 + c] = h_init[c];
    }

    // x staging: thread -> (row, 16B chunk)
    const int xrow = tid >> 4, xcc = tid & 15;
    const uint4* xg = reinterpret_cast<const uint4*>(X2 + (size_t)(b0 + xrow) * NIN + xcc * 8);
    unsigned short* xdst = &x_lds[xrow * 136 + xcc * 8];

    // W pointers
    const unsigned char* w1base = W1 + ((size_t)(w * 4) * 64 + l) * 24;  // +s*49152 +c*1536 (fp6)
    const unsigned char* w2base = W2 + (size_t)w * 8192 + (size_t)l * 32; // +s*65536 +nt*2048 (fp8)

    // prime pipeline: x[0] -> LDS, x[1] -> reg
    *reinterpret_cast<uint4*>(xdst) = xg[0];
    uint4 xnext = xg[16];
    frag32 w1buf[4];                // Phase A B-frags fp6 (valid from it0 s==23 on)
    __syncthreads();

    const float DSCL = 4.76837158203125e-07f;  // 2^-21: undo h x2^8 * W1 x2^13
    const float TS   = 1.0f / 65536.0f;        // 2^-16: undo W2 x2^12 and x-r x2^4
    f32x4 tacc[2][4];

    for (int it = 0; it < 5; ++it) {
        #pragma unroll
        for (int m = 0; m < 2; ++m)
            #pragma unroll
            for (int nt = 0; nt < 4; ++nt)
                tacc[m][nt] = (f32x4){0.f, 0.f, 0.f, 0.f};

        for (int s = 0; s < 24; ++s) {
            const int sn  = (s + 1 == 24) ? 0 : s + 1;
            const int sn2 = (s + 2 >= 24) ? (s + 2 - 24) : s + 2;

            // ---- issue W2[s] loads (4 x 32B fp8 frags; consumed after barrier A)
            frag32 w2v[4];
            {
                const unsigned char* w2p = w2base + (size_t)s * 65536;
                #pragma unroll
                for (int nt = 0; nt < 4; ++nt) {
                    const uint4* p = reinterpret_cast<const uint4*>(w2p + nt * 2048);
                    w2v[nt].q[0] = p[0];
                    w2v[nt].q[1] = p[1];
                }
            }

            f32x4 d0 = {0,0,0,0}, d1 = {0,0,0,0};
            float dv = 0.f;
            if (it == 0) {
                dv = d0inv[s * 128 + w * 16 + lo];   // exact it0 denom reciprocal
            } else {
                // ---- Phase A: h fp8 (A) x W1 fp6 (B), minimal transients
                #pragma unroll
                for (int c = 0; c < 4; ++c) {
                    frag32 ha0, ha1;
                    const uint4* p0 = reinterpret_cast<const uint4*>(
                        &h8_lds[lo * 528 + c * 128 + hi * 32]);
                    const uint4* p1 = reinterpret_cast<const uint4*>(
                        &h8_lds[(16 + lo) * 528 + c * 128 + hi * 32]);
                    ha0.q[0] = p0[0]; ha0.q[1] = p0[1];
                    ha1.q[0] = p1[0]; ha1.q[1] = p1[1];
                    d0 = MFMA128_F6(ha0.v, w1buf[c].v, d0);
                    d1 = MFMA128_F6(ha1.v, w1buf[c].v, d1);
                }
            }

            // ---- r = x * rcp(denom + eps) -> fp8 in r8_lds  (x pre-scaled x16)
            #pragma unroll
            for (int i = 0; i < 4; ++i) {
                int row0 = hi * 4 + i;
                float x0 = bf2f(x_lds[row0 * 136 + w * 16 + lo]);
                float x1 = bf2f(x_lds[(16 + row0) * 136 + w * 16 + lo]);
                float r0, r1;
                if (it == 0) { r0 = x0 * dv; r1 = x1 * dv; }
                else {
                    r0 = x0 * __builtin_amdgcn_rcpf(fmaf(d0[i], DSCL, 1e-20f));
                    r1 = x1 * __builtin_amdgcn_rcpf(fmaf(d1[i], DSCL, 1e-20f));
                }
                int c0 = __builtin_amdgcn_cvt_pk_fp8_f32(r0, r0, 0, false);
                int c1 = __builtin_amdgcn_cvt_pk_fp8_f32(r1, r1, 0, false);
                r8_lds[row0 * 144 + w * 16 + lo] = (unsigned char)(c0 & 0xff);
                r8_lds[(16 + row0) * 144 + w * 16 + lo] = (unsigned char)(c1 & 0xff);
            }
            LDS_BARRIER();   // barrier A (LDS-only: global prefetches stay in flight)

            // ---- Phase B: r8 frags (fp8) x w2v (fp8)
            frag32 ra0, ra1;
            {
                const uint4* p0 = reinterpret_cast<const uint4*>(&r8_lds[lo * 144 + hi * 32]);
                const uint4* p1 = reinterpret_cast<const uint4*>(&r8_lds[(16 + lo) * 144 + hi * 32]);
                ra0.q[0] = p0[0]; ra0.q[1] = p0[1];
                ra1.q[0] = p1[0]; ra1.q[1] = p1[1];
            }
            #pragma unroll
            for (int nt = 0; nt < 2; ++nt) {
                tacc[0][nt] = MFMA128(ra0.v, w2v[nt].v, tacc[0][nt]);
                tacc[1][nt] = MFMA128(ra1.v, w2v[nt].v, tacc[1][nt]);
            }

            // ---- reload w1buf = W1[sn] fp6 (skip during it0 except last slot)
            if (it > 0 || s == 23) {
                const unsigned char* w1p = w1base + (size_t)sn * 49152;
                #pragma unroll
                for (int c = 0; c < 4; ++c)
                    load6(w1buf[c], w1p + c * 1536);
            }

            #pragma unroll
            for (int nt = 2; nt < 4; ++nt) {
                tacc[0][nt] = MFMA128(ra0.v, w2v[nt].v, tacc[0][nt]);
                tacc[1][nt] = MFMA128(ra1.v, w2v[nt].v, tacc[1][nt]);
            }

            // ---- stage x[s+1] (loaded last slot), issue x[s+2]
            *reinterpret_cast<uint4*>(xdst) = xnext;
            xnext = xg[(size_t)sn2 * 16];
            LDS_BARRIER();   // barrier B
        }

        // ---- boundary: h_new = normalize(h * (1 + t*2^-16)), fp32 master in LDS
        float hv_[2][4][4];
        float p[2][4];
        #pragma unroll
        for (int m = 0; m < 2; ++m)
            #pragma unroll
            for (int i = 0; i < 4; ++i) p[m][i] = 0.f;

        #pragma unroll
        for (int m = 0; m < 2; ++m)
            #pragma unroll
            for (int nt = 0; nt < 4; ++nt)
                #pragma unroll
                for (int i = 0; i < 4; ++i) {
                    int row = m * 16 + hi * 4 + i;
                    int col = w * 64 + nt * 16 + lo;
                    float hv = h32_lds[row * 516 + col];
                    float v = hv * (1.f + tacc[m][nt][i] * TS);  // EPSILON_0 = 1
                    hv_[m][nt][i] = v;
                    p[m][i] += v;
                }
        #pragma unroll
        for (int mask = 1; mask < 16; mask <<= 1)
            #pragma unroll
            for (int m = 0; m < 2; ++m)
                #pragma unroll
                for (int i = 0; i < 4; ++i)
                    p[m][i] += __shfl_xor(p[m][i], mask, 64);
        if (lo == 0) {
            #pragma unroll
            for (int m = 0; m < 2; ++m)
                #pragma unroll
                for (int i = 0; i < 4; ++i)
                    red[w][m * 16 + hi * 4 + i] = p[m][i];
        }
        __syncthreads();
        float inv[2][4];
        #pragma unroll
        for (int m = 0; m < 2; ++m)
            #pragma unroll
            for (int i = 0; i < 4; ++i) {
                int row = m * 16 + hi * 4 + i;
                float S = 0.f;
                #pragma unroll
                for (int ww = 0; ww < 8; ++ww) S += red[ww][row];
                inv[m][i] = 1.f / (S + 1e-20f);
            }

        if (it < 4) {
            #pragma unroll
            for (int m = 0; m < 2; ++m)
                #pragma unroll
                for (int nt = 0; nt < 4; ++nt)
                    #pragma unroll
                    for (int i = 0; i < 4; ++i) {
                        int row = m * 16 + hi * 4 + i;
                        int col = w * 64 + nt * 16 + lo;
                        float hv = hv_[m][nt][i] * inv[m][i];
                        h32_lds[row * 516 + col] = hv;
                        int c = __builtin_amdgcn_cvt_pk_fp8_f32(hv * 256.0f, hv * 256.0f, 0, false);
                        h8_lds[row * 528 + col] = (unsigned char)(c & 0xff);
                    }
            __syncthreads();
        } else {
            #pragma unroll
            for (int m = 0; m < 2; ++m)
                #pragma unroll
                for (int nt = 0; nt < 4; ++nt)
                    #pragma unroll
                    for (int i = 0; i < 4; ++i) {
                        int row = m * 16 + hi * 4 + i;
                        int col = w * 64 + nt * 16 + lo;
                        out[(size_t)(b0 + row) * 512 + col] = hv_[m][nt][i] * inv[m][i];
                    }
        }
    }
}

extern "C" void kernel_launch(void* const* d_in, const int* in_sizes, int n_in,
                              void* d_out, int out_size, void* d_ws, size_t ws_size,
                              hipStream_t stream) {
    const float* x   = (const float*)d_in[0];   // [8192][3072]
    const float* wgt = (const float*)d_in[1];   // [512][3072]
    const float* h0  = (const float*)d_in[2];   // [512]
    float* out = (float*)d_out;

    // ws: X2 bf16 50,331,648 | W1 fp6 1,179,648 | W2 fp8 1,572,864 | d0inv 12,288
    unsigned short* X2 = (unsigned short*)d_ws;
    unsigned char*  W1 = (unsigned char*)((char*)d_ws + 50331648);
    unsigned char*  W2 = (unsigned char*)((char*)d_ws + 51511296);
    float* d0inv       = (float*)((char*)d_ws + 53084160);

    prep_all<<<8672, 256, 0, stream>>>(x, wgt, h0, X2, W1, W2, d0inv);
    nnmf_main<<<256, 512, 0, stream>>>(X2, W1, W2, d0inv, h0, out);
}